// Round 2
// baseline (586.982 us; speedup 1.0000x reference)
//
#include <hip/hip_runtime.h>
#include <math.h>

#define NB 8
#define IN_CH 2
#define OUT_CHN 4
#define NSINC 4
#define CONDC 32
#define KK 256
#define HOP 64
#define TT 65536
#define NF 1025
#define LL (HOP*(NF-1)+KK)   /* 65792 */
#define PI_F 3.14159265358979323846f

/* ws layout (floats):
   w1t : [32][256][32]  = 262144   off 0
   h   : [B][NF][32]    = 262400   off 262144
   par : [B][NF][64]    = 524800   off 524544
   acc : [B][O][LL]     = 2105344  off 1049344
   total 3,154,688 floats = 12.6 MB */
#define W1T_OFF 0
#define H_OFF   262144
#define PAR_OFF 524544
#define ACC_OFF 1049344
#define ACC_N   2105344

__global__ void k_transpose_w1(const float* __restrict__ w1, float* __restrict__ w1t) {
    int u = blockIdx.x * 256 + threadIdx.x;
    if (u < CONDC * CONDC * KK) {
        int c = u & 31;
        int k = (u >> 5) & 255;
        int cin = u >> 13;
        w1t[u] = w1[(c * CONDC + cin) * KK + k];
    }
}

__global__ __launch_bounds__(256) void k_hconv(const float* __restrict__ cond,
                                               const float* __restrict__ w1t,
                                               const float* __restrict__ b1,
                                               float* __restrict__ h_out) {
    __shared__ __align__(16) float s_cond[CONDC][448];
    __shared__ float s_red[256];
    const int tile = blockIdx.x;
    const int b = blockIdx.y;
    const int f0 = tile * 4;
    const long pos0 = (long)f0 * HOP - 128;

    for (int u = threadIdx.x; u < CONDC * 448; u += 256) {
        int cin = u / 448;
        int idx = u - cin * 448;
        long p = pos0 + idx;
        float v = 0.f;
        if (p >= 0 && p < TT) v = cond[((long)b * CONDC + cin) * TT + p];
        s_cond[cin][idx] = v;
    }
    __syncthreads();

    const int c = threadIdx.x & 31;
    const int q = threadIdx.x >> 5;
    const int fj = q & 3;
    const int half = q >> 2;
    const int f = f0 + fj;
    float acc = 0.f;
    if (f < NF) {
        const int cin0 = half * 16;
        for (int cin = cin0; cin < cin0 + 16; ++cin) {
            const float* wrow = w1t + (cin * KK) * CONDC + c;
            const float4* crow = (const float4*)&s_cond[cin][fj * HOP];
            #pragma unroll 8
            for (int k4 = 0; k4 < 64; ++k4) {
                float4 cv = crow[k4];
                const float* wp = wrow + (k4 * 4) * CONDC;
                acc += wp[0] * cv.x + wp[CONDC] * cv.y + wp[2 * CONDC] * cv.z + wp[3 * CONDC] * cv.w;
            }
        }
    }
    s_red[threadIdx.x] = acc;
    __syncthreads();
    if (half == 0 && f < NF) {
        float hv = s_red[threadIdx.x] + s_red[threadIdx.x + 128] + b1[c];
        h_out[((long)b * NF + f) * CONDC + c] = hv;
    }
}

__global__ __launch_bounds__(64) void k_params(const float* __restrict__ h,
                                               const float* __restrict__ w2,
                                               const float* __restrict__ b2,
                                               float* __restrict__ par) {
    __shared__ float s_h[CONDC];
    const int f = blockIdx.x;
    const int b = blockIdx.y;
    const int t = threadIdx.x;
    if (t < CONDC) {
        float v = h[((long)b * NF + f) * CONDC + t];
        s_h[t] = (v >= 0.f) ? v : 0.01f * v;
    }
    __syncthreads();
    float acc = b2[t];
    #pragma unroll 8
    for (int cin = 0; cin < CONDC; ++cin) acc += s_h[cin] * w2[t * CONDC + cin];
    par[((long)b * NF + f) * 64 + t] = tanhf(acc);
}

__device__ __forceinline__ float sinc_ref(float x) {
    float px = PI_F * x;
    if (fabsf(px) < 1e-4f) return 1.f - px * px * (1.f / 6.f);
    return sinf(px) / px;
}

__global__ __launch_bounds__(256) void k_sincconv(const float* __restrict__ x,
                                                  const float* __restrict__ par,
                                                  float* __restrict__ accbuf) {
    __shared__ __align__(16) float s_frame[4][IN_CH][KK];
    __shared__ __align__(16) float s_filt[4][IN_CH][KK];
    __shared__ float s_par[4][16];
    const int tile = blockIdx.x;
    const int o = blockIdx.y;
    const int b = blockIdx.z;
    const int f0 = tile * 4;
    const int t = threadIdx.x;

    if (t < 64) {
        int j = t >> 4;
        int u = t & 15;
        int f = f0 + j;
        float v = 0.f;
        if (f < NF) {
            int c2 = (u < 8) ? (o * 8 + u) : (32 + o * 8 + (u - 8));
            v = par[((long)b * NF + f) * 64 + c2];
        }
        s_par[j][u] = v;
    }
    __syncthreads();

    const int k = t;
    const float ta = ((float)k - 128.f) * (1.f / 256.f);
    const float ang = (2.f * PI_F / 256.f) * (float)k;
    const float c1 = cosf(ang);
    const float c2v = cosf(2.f * ang);
    const float ola_k = 0.5f * (1.f - c1);
    const float fir_k = 0.42f - 0.5f * c1 + 0.08f * c2v;
    const float fscale = fir_k * (1.f / (NSINC * KK));

    for (int j = 0; j < 4; ++j) {
        int f = f0 + j;
        if (f < NF) {
            for (int i = 0; i < IN_CH; ++i) {
                long jg = (long)f * HOP + k;
                long pos = jg - 128;
                if (pos < 0) pos = -pos;
                else if (pos >= TT) pos = 2 * (TT - 1) - pos;
                float xv = x[((long)b * IN_CH + i) * TT + pos];
                s_frame[j][i][k] = xv * ola_k;

                float a0 = s_par[j][i * 4 + 0], a1 = s_par[j][i * 4 + 1];
                float a2 = s_par[j][i * 4 + 2], a3 = s_par[j][i * 4 + 3];
                float w0 = s_par[j][8 + i * 4 + 0], w1v = s_par[j][8 + i * 4 + 1];
                float w2v = s_par[j][8 + i * 4 + 2], w3v = s_par[j][8 + i * 4 + 3];
                float sv = a0 * sinc_ref(w0 * ta + 1e-6f) + a1 * sinc_ref(w1v * ta + 1e-6f)
                         + a2 * sinc_ref(w2v * ta + 1e-6f) + a3 * sinc_ref(w3v * ta + 1e-6f);
                s_filt[j][i][k] = sv * fscale;
            }
        }
    }
    __syncthreads();

    const int w = t >> 6;
    const int l = t & 63;
    const int f = f0 + w;
    if (f < NF) {
        float acc0 = 0.f, acc1 = 0.f, acc2 = 0.f, acc3 = 0.f;
        for (int i = 0; i < IN_CH; ++i) {
            const float4* filt4 = (const float4*)s_filt[w][i];
            const float4* fr4 = (const float4*)s_frame[w][i];
            float4 F1 = filt4[l];
            #pragma unroll 4
            for (int q = 0; q < 64; ++q) {
                float4 fr = fr4[q];
                float4 F0 = filt4[(l - q - 1) & 63];
                acc0 += fr.x * F1.x + fr.y * F0.w + fr.z * F0.z + fr.w * F0.y;
                acc1 += fr.x * F1.y + fr.y * F1.x + fr.z * F0.w + fr.w * F0.z;
                acc2 += fr.x * F1.z + fr.y * F1.y + fr.z * F1.x + fr.w * F0.w;
                acc3 += fr.x * F1.w + fr.y * F1.z + fr.z * F1.y + fr.w * F1.x;
                F1 = F0;
            }
        }
        long base = ((long)(b * OUT_CHN + o)) * LL + (long)f * HOP + 4 * l;
        #pragma unroll
        for (int jj = 0; jj < 4; ++jj) {
            int n = 4 * l + jj;
            float angn = (2.f * PI_F / 256.f) * (float)n;
            float olan = 0.5f * (1.f - cosf(angn));
            float v = (jj == 0 ? acc0 : jj == 1 ? acc1 : jj == 2 ? acc2 : acc3);
            atomicAdd(&accbuf[base + jj], v * olan);
        }
    }
}

__global__ __launch_bounds__(256) void k_norm(const float* __restrict__ accbuf,
                                              const float* __restrict__ bias,
                                              float* __restrict__ out) {
    int idx = blockIdx.x * 256 + threadIdx.x;
    if (idx >= NB * OUT_CHN * TT) return;
    int tpos = idx & (TT - 1);
    int bo = idx >> 16;
    int o = bo & 3;
    int tt = tpos + 128;
    float env = 0.f;
    int fhi = tt >> 6;
    #pragma unroll
    for (int d = 0; d < 4; ++d) {
        int f = fhi - d;
        int n = tt - f * HOP;
        if (f >= 0 && f < NF && n >= 0 && n < KK) {
            float angn = (2.f * PI_F / 256.f) * (float)n;
            float wv = 0.5f * (1.f - cosf(angn));
            env += wv * wv;
        }
    }
    out[idx] = accbuf[(long)bo * LL + tt] / env + bias[o];
}

extern "C" void kernel_launch(void* const* d_in, const int* in_sizes, int n_in,
                              void* d_out, int out_size, void* d_ws, size_t ws_size,
                              hipStream_t stream) {
    const float* x    = (const float*)d_in[0];
    const float* cond = (const float*)d_in[1];
    const float* w1   = (const float*)d_in[2];
    const float* b1   = (const float*)d_in[3];
    const float* w2   = (const float*)d_in[4];
    const float* b2   = (const float*)d_in[5];
    const float* bias = (const float*)d_in[6];
    float* out = (float*)d_out;
    float* ws  = (float*)d_ws;
    float* w1t = ws + W1T_OFF;
    float* h   = ws + H_OFF;
    float* par = ws + PAR_OFF;
    float* acc = ws + ACC_OFF;

    (void)hipMemsetAsync(acc, 0, (size_t)ACC_N * sizeof(float), stream);
    hipLaunchKernelGGL(k_transpose_w1, dim3(1024), dim3(256), 0, stream, w1, w1t);
    hipLaunchKernelGGL(k_hconv, dim3(257, NB), dim3(256), 0, stream, cond, w1t, b1, h);
    hipLaunchKernelGGL(k_params, dim3(NF, NB), dim3(64), 0, stream, h, w2, b2, par);
    hipLaunchKernelGGL(k_sincconv, dim3(257, OUT_CHN, NB), dim3(256), 0, stream, x, par, acc);
    hipLaunchKernelGGL(k_norm, dim3(8192), dim3(256), 0, stream, acc, bias, out);
}

// Round 3
// 580.465 us; speedup vs baseline: 1.0112x; 1.0112x over previous
//
#include <hip/hip_runtime.h>
#include <math.h>

#define NB 8
#define IN_CH 2
#define OUT_CHN 4
#define NSINC 4
#define CONDC 32
#define KK 256
#define HOP 64
#define TT 65536
#define NF 1025
#define LL (HOP*(NF-1)+KK)   /* 65792 */
#define PI_F 3.14159265358979323846f

/* ws layout (floats): h @262144, par @524544, acc @1049344 */
#define H_OFF   262144
#define PAR_OFF 524544
#define ACC_OFF 1049344
#define ACC_N   2105344

/* ---- h = leaky-prep conv: h[b][f][c] = sum_cin sum_k cond[b][cin][f*64+k-128] * w1[c][cin][k] + b1[c]
   Block: 32 frames x 32 channels. LDS-staged w1 slice + cond tile per cin, XOR-swizzled.
   Threads: 256 = 8 k-subgroups x 32 lanes; lane tile = 8f x 4c; k-window 32. */
__global__ __launch_bounds__(256) void k_hconv2(const float* __restrict__ cond,
                                                const float* __restrict__ w1,
                                                const float* __restrict__ b1,
                                                float* __restrict__ h_out) {
    __shared__ __align__(16) float smem[16384];  /* 64 KB: [0..8191] w1 slice, [8192..16383] cond tile */
    float* s_w1 = smem;
    float* s_cd = smem + 8192;
    const int t = threadIdx.x;
    const int tile = blockIdx.x;
    const int b = blockIdx.y;
    const int f0 = tile * 32;
    const long pos0 = (long)f0 * HOP - 128;

    const int sg = t >> 5;          /* k-subgroup 0..7 */
    const int lane32 = t & 31;
    const int fg = lane32 >> 3;     /* 0..3 : frames fg*8..fg*8+7 */
    const int cg = lane32 & 7;      /* 0..7 : channels cg*4..cg*4+3 */
    const int kbase = sg * 32;

    float acc[8][4];
    #pragma unroll
    for (int i = 0; i < 8; ++i)
        #pragma unroll
        for (int j = 0; j < 4; ++j) acc[i][j] = 0.f;

    for (int cin = 0; cin < CONDC; ++cin) {
        __syncthreads();            /* previous compute done before overwrite */
        /* stage w1 slice: s_w1[c][k] = w1[(c*32+cin)*256+k], swizzle idx ^= ((c>>2)&7)<<2 */
        #pragma unroll
        for (int ii = 0; ii < 8; ++ii) {
            int s = ii * 256 + t;
            int c = s >> 6, k4 = s & 63;
            float4 v = *(const float4*)&w1[((c * CONDC + cin) << 8) + (k4 << 2)];
            int fi = (((c << 8) + (k4 << 2))) ^ (((c >> 2) & 7) << 2);
            *(float4*)&s_w1[fi] = v;
        }
        /* stage cond tile: s_cd[fl][k] = cond[b][cin][pos0+fl*64+k] (zero-pad), swizzle ^= ((fl>>3)&3)<<2 */
        #pragma unroll
        for (int ii = 0; ii < 8; ++ii) {
            int s = ii * 256 + t;
            int fl = s >> 6, k4 = s & 63;
            long p = pos0 + fl * HOP + (k4 << 2);
            float4 v = make_float4(0.f, 0.f, 0.f, 0.f);
            if (p >= 0 && p < TT) v = *(const float4*)&cond[((long)b * CONDC + cin) * TT + p];
            int fi = (((fl << 8) + (k4 << 2))) ^ (((fl >> 3) & 3) << 2);
            *(float4*)&s_cd[fi] = v;
        }
        __syncthreads();
        /* compute: 8 k4-steps x (4 w1 frags + 8 cond frags + 128 fma) */
        #pragma unroll
        for (int k4 = 0; k4 < 8; ++k4) {
            const int kk = kbase + (k4 << 2);
            float4 wf[4], cf[8];
            #pragma unroll
            for (int j = 0; j < 4; ++j) {
                int c = cg * 4 + j;
                wf[j] = *(const float4*)&s_w1[((c << 8) + kk) ^ (((c >> 2) & 7) << 2)];
            }
            #pragma unroll
            for (int i = 0; i < 8; ++i) {
                int fl = fg * 8 + i;
                cf[i] = *(const float4*)&s_cd[((fl << 8) + kk) ^ (((fl >> 3) & 3) << 2)];
            }
            #pragma unroll
            for (int i = 0; i < 8; ++i)
                #pragma unroll
                for (int j = 0; j < 4; ++j)
                    acc[i][j] += cf[i].x * wf[j].x + cf[i].y * wf[j].y
                               + cf[i].z * wf[j].z + cf[i].w * wf[j].w;
        }
    }

    /* reduce 2 k-subgroups within wave (lanes L, L^32 share (f,c) tile) */
    #pragma unroll
    for (int i = 0; i < 8; ++i)
        #pragma unroll
        for (int j = 0; j < 4; ++j) {
            float v = acc[i][j];
            v += __shfl_xor(v, 32);
            acc[i][j] = v;
        }
    __syncthreads();
    float* s_red = smem;            /* [4 wave][32 f][32 c] = 4096 floats */
    const int wv = t >> 6;
    if ((t & 63) < 32) {
        #pragma unroll
        for (int i = 0; i < 8; ++i) {
            float4 o = make_float4(acc[i][0], acc[i][1], acc[i][2], acc[i][3]);
            *(float4*)&s_red[wv * 1024 + (fg * 8 + i) * 32 + cg * 4] = o;
        }
    }
    __syncthreads();
    {
        int f = t >> 3;
        int c4 = t & 7;
        float4 r = make_float4(0.f, 0.f, 0.f, 0.f);
        #pragma unroll
        for (int w = 0; w < 4; ++w) {
            float4 p = *(const float4*)&s_red[w * 1024 + f * 32 + c4 * 4];
            r.x += p.x; r.y += p.y; r.z += p.z; r.w += p.w;
        }
        const float4 bb = *(const float4*)&b1[c4 * 4];
        int fglob = f0 + f;
        if (fglob < NF) {
            float4 o = make_float4(r.x + bb.x, r.y + bb.y, r.z + bb.z, r.w + bb.w);
            *(float4*)&h_out[((long)b * NF + fglob) * CONDC + c4 * 4] = o;
        }
    }
}

__global__ __launch_bounds__(64) void k_params(const float* __restrict__ h,
                                               const float* __restrict__ w2,
                                               const float* __restrict__ b2,
                                               float* __restrict__ par) {
    __shared__ float s_h[CONDC];
    const int f = blockIdx.x;
    const int b = blockIdx.y;
    const int t = threadIdx.x;
    if (t < CONDC) {
        float v = h[((long)b * NF + f) * CONDC + t];
        s_h[t] = (v >= 0.f) ? v : 0.01f * v;
    }
    __syncthreads();
    float acc = b2[t];
    #pragma unroll 8
    for (int cin = 0; cin < CONDC; ++cin) acc += s_h[cin] * w2[t * CONDC + cin];
    par[((long)b * NF + f) * 64 + t] = tanhf(acc);
}

__device__ __forceinline__ float sinc_ref(float x) {
    float px = PI_F * x;
    if (fabsf(px) < 1e-4f) return 1.f - px * px * (1.f / 6.f);
    return sinf(px) / px;
}

__global__ __launch_bounds__(256) void k_sincconv(const float* __restrict__ x,
                                                  const float* __restrict__ par,
                                                  float* __restrict__ accbuf) {
    __shared__ __align__(16) float s_frame[4][IN_CH][KK];
    __shared__ __align__(16) float s_filt[4][IN_CH][KK];
    __shared__ float s_par[4][16];
    const int tile = blockIdx.x;
    const int o = blockIdx.y;
    const int b = blockIdx.z;
    const int f0 = tile * 4;
    const int t = threadIdx.x;

    if (t < 64) {
        int j = t >> 4;
        int u = t & 15;
        int f = f0 + j;
        float v = 0.f;
        if (f < NF) {
            int c2 = (u < 8) ? (o * 8 + u) : (32 + o * 8 + (u - 8));
            v = par[((long)b * NF + f) * 64 + c2];
        }
        s_par[j][u] = v;
    }
    __syncthreads();

    const int k = t;
    const float ta = ((float)k - 128.f) * (1.f / 256.f);
    const float ang = (2.f * PI_F / 256.f) * (float)k;
    const float c1 = cosf(ang);
    const float c2v = cosf(2.f * ang);
    const float ola_k = 0.5f * (1.f - c1);
    const float fir_k = 0.42f - 0.5f * c1 + 0.08f * c2v;
    const float fscale = fir_k * (1.f / (NSINC * KK));

    for (int j = 0; j < 4; ++j) {
        int f = f0 + j;
        if (f < NF) {
            for (int i = 0; i < IN_CH; ++i) {
                long jg = (long)f * HOP + k;
                long pos = jg - 128;
                if (pos < 0) pos = -pos;
                else if (pos >= TT) pos = 2 * (TT - 1) - pos;
                float xv = x[((long)b * IN_CH + i) * TT + pos];
                s_frame[j][i][k] = xv * ola_k;

                float a0 = s_par[j][i * 4 + 0], a1 = s_par[j][i * 4 + 1];
                float a2 = s_par[j][i * 4 + 2], a3 = s_par[j][i * 4 + 3];
                float w0 = s_par[j][8 + i * 4 + 0], w1v = s_par[j][8 + i * 4 + 1];
                float w2v = s_par[j][8 + i * 4 + 2], w3v = s_par[j][8 + i * 4 + 3];
                float sv = a0 * sinc_ref(w0 * ta + 1e-6f) + a1 * sinc_ref(w1v * ta + 1e-6f)
                         + a2 * sinc_ref(w2v * ta + 1e-6f) + a3 * sinc_ref(w3v * ta + 1e-6f);
                s_filt[j][i][k] = sv * fscale;
            }
        }
    }
    __syncthreads();

    const int w = t >> 6;
    const int l = t & 63;
    const int f = f0 + w;
    if (f < NF) {
        float acc0 = 0.f, acc1 = 0.f, acc2 = 0.f, acc3 = 0.f;
        for (int i = 0; i < IN_CH; ++i) {
            const float4* filt4 = (const float4*)s_filt[w][i];
            const float4* fr4 = (const float4*)s_frame[w][i];
            float4 F1 = filt4[l];
            #pragma unroll 4
            for (int q = 0; q < 64; ++q) {
                float4 fr = fr4[q];
                float4 F0 = filt4[(l - q - 1) & 63];
                acc0 += fr.x * F1.x + fr.y * F0.w + fr.z * F0.z + fr.w * F0.y;
                acc1 += fr.x * F1.y + fr.y * F1.x + fr.z * F0.w + fr.w * F0.z;
                acc2 += fr.x * F1.z + fr.y * F1.y + fr.z * F1.x + fr.w * F0.w;
                acc3 += fr.x * F1.w + fr.y * F1.z + fr.z * F1.y + fr.w * F1.x;
                F1 = F0;
            }
        }
        long base = ((long)(b * OUT_CHN + o)) * LL + (long)f * HOP + 4 * l;
        #pragma unroll
        for (int jj = 0; jj < 4; ++jj) {
            int n = 4 * l + jj;
            float angn = (2.f * PI_F / 256.f) * (float)n;
            float olan = 0.5f * (1.f - cosf(angn));
            float v = (jj == 0 ? acc0 : jj == 1 ? acc1 : jj == 2 ? acc2 : acc3);
            atomicAdd(&accbuf[base + jj], v * olan);
        }
    }
}

__global__ __launch_bounds__(256) void k_norm(const float* __restrict__ accbuf,
                                              const float* __restrict__ bias,
                                              float* __restrict__ out) {
    int idx = blockIdx.x * 256 + threadIdx.x;
    if (idx >= NB * OUT_CHN * TT) return;
    int tpos = idx & (TT - 1);
    int bo = idx >> 16;
    int o = bo & 3;
    int tt = tpos + 128;
    float env = 0.f;
    int fhi = tt >> 6;
    #pragma unroll
    for (int d = 0; d < 4; ++d) {
        int f = fhi - d;
        int n = tt - f * HOP;
        if (f >= 0 && f < NF && n >= 0 && n < KK) {
            float angn = (2.f * PI_F / 256.f) * (float)n;
            float wv = 0.5f * (1.f - cosf(angn));
            env += wv * wv;
        }
    }
    out[idx] = accbuf[(long)bo * LL + tt] / env + bias[o];
}

extern "C" void kernel_launch(void* const* d_in, const int* in_sizes, int n_in,
                              void* d_out, int out_size, void* d_ws, size_t ws_size,
                              hipStream_t stream) {
    const float* x    = (const float*)d_in[0];
    const float* cond = (const float*)d_in[1];
    const float* w1   = (const float*)d_in[2];
    const float* b1   = (const float*)d_in[3];
    const float* w2   = (const float*)d_in[4];
    const float* b2   = (const float*)d_in[5];
    const float* bias = (const float*)d_in[6];
    float* out = (float*)d_out;
    float* ws  = (float*)d_ws;
    float* h   = ws + H_OFF;
    float* par = ws + PAR_OFF;
    float* acc = ws + ACC_OFF;

    (void)hipMemsetAsync(acc, 0, (size_t)ACC_N * sizeof(float), stream);
    hipLaunchKernelGGL(k_hconv2, dim3(33, NB), dim3(256), 0, stream, cond, w1, b1, h);
    hipLaunchKernelGGL(k_params, dim3(NF, NB), dim3(64), 0, stream, h, w2, b2, par);
    hipLaunchKernelGGL(k_sincconv, dim3(257, OUT_CHN, NB), dim3(256), 0, stream, x, par, acc);
    hipLaunchKernelGGL(k_norm, dim3(8192), dim3(256), 0, stream, acc, bias, out);
}

// Round 4
// 300.607 us; speedup vs baseline: 1.9527x; 1.9310x over previous
//
#include <hip/hip_runtime.h>
#include <math.h>

#define NB 8
#define IN_CH 2
#define OUT_CHN 4
#define NSINC 4
#define CONDC 32
#define KK 256
#define HOP 64
#define TT 65536
#define NF 1025
#define LL (HOP*(NF-1)+KK)   /* 65792 */
#define PI_F 3.14159265358979323846f

/* ws layout (floats):
   par    @ 0        : 524800
   acc    @ 524800   : 2105344  (also aliased by h_part: 4*8*1025*32 = 1049600, consumed before memset)
   total 2,630,144 floats = 10.5 MB */
#define PAR_OFF 0
#define ACC_OFF 524800
#define ACC_N   2105344
#define HPART_OFF ACC_OFF

typedef __attribute__((ext_vector_type(8))) short bf16x8;
typedef __attribute__((ext_vector_type(4))) float f32x4;

__device__ __forceinline__ void splitbf(float v, unsigned short& hi, unsigned short& lo) {
    unsigned bits = __float_as_uint(v);
    hi = (unsigned short)(bits >> 16);
    float r = v - __uint_as_float(bits & 0xffff0000u);
    lo = (unsigned short)(__float_as_uint(r) >> 16);
}

/* ---- hconv as split-bf16 MFMA GEMM ----
   h[b][f][c] = sum_{cin,k} cond[b][cin][f*64+k-128] * w1[c][cin][k]
   Block: 64 frames x 32 ch, 8 cins (cin-group g). 4 waves, each 16 frames.
   A: staged cond window 4288 samples (pad +8 elems per 64) as hi/lo bf16.
   B: staged w1 slice [32][256+8] hi/lo bf16.
   mfma_f32_16x16x32_bf16: A row=lane&15, k-octet=lane>>4; B col=lane&15;
   D col=lane&15, row=(lane>>4)*4+reg. */
__global__ __launch_bounds__(256) void k_hconv3(const float* __restrict__ cond,
                                                const float* __restrict__ w1,
                                                float* __restrict__ h_part) {
    __shared__ __align__(16) unsigned short s_a_hi[4824];
    __shared__ __align__(16) unsigned short s_a_lo[4824];
    __shared__ __align__(16) unsigned short s_b_hi[32 * 264];
    __shared__ __align__(16) unsigned short s_b_lo[32 * 264];
    const int t = threadIdx.x;
    const int ftile = blockIdx.x;   /* 0..16 */
    const int g = blockIdx.y;       /* cin group 0..3 */
    const int b = blockIdx.z;
    const int f0 = ftile * 64;
    const long pos0 = (long)f0 * HOP - 128;
    const int w = t >> 6;
    const int l = t & 63;
    const int sel16 = l & 15;       /* A-row / B-col / D-col selector */
    const int koct = l >> 4;

    f32x4 acc0 = {0.f, 0.f, 0.f, 0.f};
    f32x4 acc1 = {0.f, 0.f, 0.f, 0.f};

    for (int ci = 0; ci < 8; ++ci) {
        const int cin = g * 8 + ci;
        __syncthreads();
        /* stage A: 4288 cond samples, reflect-padded, split hi/lo */
        const float* crow = &cond[((long)b * CONDC + cin) * TT];
        for (int u = t; u < 4288; u += 256) {
            long p = pos0 + u;
            if (p < 0) p = -p;
            if (p >= TT) p = 2 * (TT - 1) - p;
            unsigned short hi, lo;
            splitbf(crow[p], hi, lo);
            int off = u + ((u >> 6) << 3);
            s_a_hi[off] = hi;
            s_a_lo[off] = lo;
        }
        /* stage B: w1[c][cin][0..255] -> s_b[c][264] */
        for (int m4 = t; m4 < 2048; m4 += 256) {
            int c = m4 >> 6;
            int k4 = (m4 & 63) << 2;
            float4 v = *(const float4*)&w1[((c * CONDC + cin) << 8) + k4];
            ushort4 hi, lo;
            splitbf(v.x, hi.x, lo.x);
            splitbf(v.y, hi.y, lo.y);
            splitbf(v.z, hi.z, lo.z);
            splitbf(v.w, hi.w, lo.w);
            int off = c * 264 + k4;
            *(ushort4*)&s_b_hi[off] = hi;
            *(ushort4*)&s_b_lo[off] = lo;
        }
        __syncthreads();
        /* compute: 8 K-steps of 32 */
        const int flocal = w * 16 + sel16;
        #pragma unroll
        for (int ks = 0; ks < 8; ++ks) {
            int u = flocal * 64 + ks * 32 + koct * 8;
            int aoff = u + ((u >> 6) << 3);
            bf16x8 ahi = *(const bf16x8*)&s_a_hi[aoff];
            bf16x8 alo = *(const bf16x8*)&s_a_lo[aoff];
            int boff0 = sel16 * 264 + ks * 32 + koct * 8;
            int boff1 = (16 + sel16) * 264 + ks * 32 + koct * 8;
            bf16x8 b0h = *(const bf16x8*)&s_b_hi[boff0];
            bf16x8 b0l = *(const bf16x8*)&s_b_lo[boff0];
            bf16x8 b1h = *(const bf16x8*)&s_b_hi[boff1];
            bf16x8 b1l = *(const bf16x8*)&s_b_lo[boff1];
            acc0 = __builtin_amdgcn_mfma_f32_16x16x32_bf16(ahi, b0h, acc0, 0, 0, 0);
            acc0 = __builtin_amdgcn_mfma_f32_16x16x32_bf16(alo, b0h, acc0, 0, 0, 0);
            acc0 = __builtin_amdgcn_mfma_f32_16x16x32_bf16(ahi, b0l, acc0, 0, 0, 0);
            acc1 = __builtin_amdgcn_mfma_f32_16x16x32_bf16(ahi, b1h, acc1, 0, 0, 0);
            acc1 = __builtin_amdgcn_mfma_f32_16x16x32_bf16(alo, b1h, acc1, 0, 0, 0);
            acc1 = __builtin_amdgcn_mfma_f32_16x16x32_bf16(ahi, b1l, acc1, 0, 0, 0);
        }
    }

    /* epilogue: D col=lane&15, row=(lane>>4)*4+j */
    #pragma unroll
    for (int j = 0; j < 4; ++j) {
        int f = f0 + w * 16 + koct * 4 + j;
        if (f < NF) {
            long base = (((long)g * NB + b) * NF + f) * CONDC;
            h_part[base + sel16] = acc0[j];
            h_part[base + 16 + sel16] = acc1[j];
        }
    }
}

__global__ __launch_bounds__(64) void k_params(const float* __restrict__ h_part,
                                               const float* __restrict__ w2,
                                               const float* __restrict__ b1,
                                               const float* __restrict__ b2,
                                               float* __restrict__ par) {
    __shared__ float s_h[CONDC];
    const int f = blockIdx.x;
    const int b = blockIdx.y;
    const int t = threadIdx.x;
    if (t < CONDC) {
        float v = b1[t];
        #pragma unroll
        for (int g = 0; g < 4; ++g)
            v += h_part[(((long)g * NB + b) * NF + f) * CONDC + t];
        s_h[t] = (v >= 0.f) ? v : 0.01f * v;
    }
    __syncthreads();
    float acc = b2[t];
    #pragma unroll 8
    for (int cin = 0; cin < CONDC; ++cin) acc += s_h[cin] * w2[t * CONDC + cin];
    par[((long)b * NF + f) * 64 + t] = tanhf(acc);
}

__device__ __forceinline__ float sinc_ref(float x) {
    float px = PI_F * x;
    if (fabsf(px) < 1e-4f) return 1.f - px * px * (1.f / 6.f);
    return sinf(px) / px;
}

__global__ __launch_bounds__(256) void k_sincconv(const float* __restrict__ x,
                                                  const float* __restrict__ par,
                                                  float* __restrict__ accbuf) {
    __shared__ __align__(16) float s_frame[4][IN_CH][KK];
    __shared__ __align__(16) float s_filt[4][IN_CH][KK];
    __shared__ float s_par[4][16];
    const int tile = blockIdx.x;
    const int o = blockIdx.y;
    const int b = blockIdx.z;
    const int f0 = tile * 4;
    const int t = threadIdx.x;

    if (t < 64) {
        int j = t >> 4;
        int u = t & 15;
        int f = f0 + j;
        float v = 0.f;
        if (f < NF) {
            int c2 = (u < 8) ? (o * 8 + u) : (32 + o * 8 + (u - 8));
            v = par[((long)b * NF + f) * 64 + c2];
        }
        s_par[j][u] = v;
    }
    __syncthreads();

    const int k = t;
    const float ta = ((float)k - 128.f) * (1.f / 256.f);
    const float ang = (2.f * PI_F / 256.f) * (float)k;
    const float c1 = cosf(ang);
    const float c2v = cosf(2.f * ang);
    const float ola_k = 0.5f * (1.f - c1);
    const float fir_k = 0.42f - 0.5f * c1 + 0.08f * c2v;
    const float fscale = fir_k * (1.f / (NSINC * KK));

    for (int j = 0; j < 4; ++j) {
        int f = f0 + j;
        if (f < NF) {
            for (int i = 0; i < IN_CH; ++i) {
                long jg = (long)f * HOP + k;
                long pos = jg - 128;
                if (pos < 0) pos = -pos;
                else if (pos >= TT) pos = 2 * (TT - 1) - pos;
                float xv = x[((long)b * IN_CH + i) * TT + pos];
                s_frame[j][i][k] = xv * ola_k;

                float a0 = s_par[j][i * 4 + 0], a1 = s_par[j][i * 4 + 1];
                float a2 = s_par[j][i * 4 + 2], a3 = s_par[j][i * 4 + 3];
                float w0 = s_par[j][8 + i * 4 + 0], w1v = s_par[j][8 + i * 4 + 1];
                float w2v = s_par[j][8 + i * 4 + 2], w3v = s_par[j][8 + i * 4 + 3];
                float sv = a0 * sinc_ref(w0 * ta + 1e-6f) + a1 * sinc_ref(w1v * ta + 1e-6f)
                         + a2 * sinc_ref(w2v * ta + 1e-6f) + a3 * sinc_ref(w3v * ta + 1e-6f);
                s_filt[j][i][k] = sv * fscale;
            }
        }
    }
    __syncthreads();

    const int w = t >> 6;
    const int l = t & 63;
    const int f = f0 + w;
    if (f < NF) {
        float acc0 = 0.f, acc1 = 0.f, acc2 = 0.f, acc3 = 0.f;
        for (int i = 0; i < IN_CH; ++i) {
            const float4* filt4 = (const float4*)s_filt[w][i];
            const float4* fr4 = (const float4*)s_frame[w][i];
            float4 F1 = filt4[l];
            #pragma unroll 4
            for (int q = 0; q < 64; ++q) {
                float4 fr = fr4[q];
                float4 F0 = filt4[(l - q - 1) & 63];
                acc0 += fr.x * F1.x + fr.y * F0.w + fr.z * F0.z + fr.w * F0.y;
                acc1 += fr.x * F1.y + fr.y * F1.x + fr.z * F0.w + fr.w * F0.z;
                acc2 += fr.x * F1.z + fr.y * F1.y + fr.z * F1.x + fr.w * F0.w;
                acc3 += fr.x * F1.w + fr.y * F1.z + fr.z * F1.y + fr.w * F1.x;
                F1 = F0;
            }
        }
        long base = ((long)(b * OUT_CHN + o)) * LL + (long)f * HOP + 4 * l;
        #pragma unroll
        for (int jj = 0; jj < 4; ++jj) {
            int n = 4 * l + jj;
            float angn = (2.f * PI_F / 256.f) * (float)n;
            float olan = 0.5f * (1.f - cosf(angn));
            float v = (jj == 0 ? acc0 : jj == 1 ? acc1 : jj == 2 ? acc2 : acc3);
            atomicAdd(&accbuf[base + jj], v * olan);
        }
    }
}

__global__ __launch_bounds__(256) void k_norm(const float* __restrict__ accbuf,
                                              const float* __restrict__ bias,
                                              float* __restrict__ out) {
    int idx = blockIdx.x * 256 + threadIdx.x;
    if (idx >= NB * OUT_CHN * TT) return;
    int tpos = idx & (TT - 1);
    int bo = idx >> 16;
    int o = bo & 3;
    int tt = tpos + 128;
    float env = 0.f;
    int fhi = tt >> 6;
    #pragma unroll
    for (int d = 0; d < 4; ++d) {
        int f = fhi - d;
        int n = tt - f * HOP;
        if (f >= 0 && f < NF && n >= 0 && n < KK) {
            float angn = (2.f * PI_F / 256.f) * (float)n;
            float wv = 0.5f * (1.f - cosf(angn));
            env += wv * wv;
        }
    }
    out[idx] = accbuf[(long)bo * LL + tt] / env + bias[o];
}

extern "C" void kernel_launch(void* const* d_in, const int* in_sizes, int n_in,
                              void* d_out, int out_size, void* d_ws, size_t ws_size,
                              hipStream_t stream) {
    const float* x    = (const float*)d_in[0];
    const float* cond = (const float*)d_in[1];
    const float* w1   = (const float*)d_in[2];
    const float* b1   = (const float*)d_in[3];
    const float* w2   = (const float*)d_in[4];
    const float* b2   = (const float*)d_in[5];
    const float* bias = (const float*)d_in[6];
    float* out = (float*)d_out;
    float* ws  = (float*)d_ws;
    float* par = ws + PAR_OFF;
    float* acc = ws + ACC_OFF;
    float* h_part = ws + HPART_OFF;   /* aliases acc; consumed before memset */

    hipLaunchKernelGGL(k_hconv3, dim3(17, 4, NB), dim3(256), 0, stream, cond, w1, h_part);
    hipLaunchKernelGGL(k_params, dim3(NF, NB), dim3(64), 0, stream, h_part, w2, b1, b2, par);
    (void)hipMemsetAsync(acc, 0, (size_t)ACC_N * sizeof(float), stream);
    hipLaunchKernelGGL(k_sincconv, dim3(257, OUT_CHN, NB), dim3(256), 0, stream, x, par, acc);
    hipLaunchKernelGGL(k_norm, dim3(8192), dim3(256), 0, stream, acc, bias, out);
}